// Round 11
// baseline (162.177 us; speedup 1.0000x reference)
//
#include <hip/hip_runtime.h>

#define N_NODES 50000
#define N_EDGES 800000
#define D 128
#define NBUCK 196   // ceil(50000/256) buckets of 256 nodes (dst>>8)
#define CAP 4800    // per-bucket capacity; mean 4096, sigma ~64 -> 11 sigma
#define CHUNK 4096  // edges per passA block (16/thread)
#define PA_BLKS ((N_EDGES + CHUNK - 1) / CHUNK)  // 196
#define FB_BLKS 12500                            // N_NODES*64/256
#define WT_BLKS 64                               // 16384/256

typedef __attribute__((ext_vector_type(8))) short short8;
typedef __attribute__((ext_vector_type(4))) float f32x4;

__device__ __forceinline__ unsigned short f2bf(float f) {
    unsigned u = __float_as_uint(f);
    u += 0x7fff + ((u >> 16) & 1);  // RNE
    return (unsigned short)(u >> 16);
}
__device__ __forceinline__ float lo16f(unsigned u) { return __uint_as_float(u << 16); }
__device__ __forceinline__ float hi16f(unsigned u) { return __uint_as_float(u & 0xffff0000u); }

// ---------------------------------------------------------------------------
// K1 (fused): passA buckets edges by dst>>8 into tmp (16 edges/thread, packed
// key = src | dlocal<<16 | bucket<<24); prep converts feature -> packed-bf16
// fb and W -> bf16 n-major Wt. gcur pre-zeroed via memsetAsync.
// ---------------------------------------------------------------------------
__global__ __launch_bounds__(256) void prep_passA(
    const float2* __restrict__ feat2, unsigned* __restrict__ fb,
    const float* __restrict__ W, unsigned short* __restrict__ Wt,
    const int* __restrict__ esrc, const int* __restrict__ edst,
    const float* __restrict__ ew, int* __restrict__ gcur,
    uint2* __restrict__ tmp) {
    __shared__ int lh[NBUCK], lbase[NBUCK], lcur[NBUCK];
    int blk = blockIdx.x, t = threadIdx.x;

    if (blk >= PA_BLKS) {
        int b2 = blk - PA_BLKS;
        if (b2 < FB_BLKS) {
            int i = b2 * 256 + t;
            float2 f = feat2[i];
            fb[i] = (unsigned)f2bf(f.x) | ((unsigned)f2bf(f.y) << 16);
        } else {
            int idx = (b2 - FB_BLKS) * 256 + t;  // 16384 weight elements
            int n = idx >> 7, k = idx & 127;
            Wt[idx] = f2bf(W[k * 128 + n]);
        }
        return;
    }

    // ---- passA ----
    for (int i = t; i < NBUCK; i += 256) lh[i] = 0;
    __syncthreads();
    int e0 = blk * CHUNK;
    unsigned key[16];
    float wv[16];
#pragma unroll
    for (int j = 0; j < 16; ++j) {
        int e = e0 + j * 256 + t;
        if (e < N_EDGES) {
            int src = esrc[e], dd = edst[e];
            key[j] = (unsigned)src | ((unsigned)(dd & 255) << 16) |
                     ((unsigned)(dd >> 8) << 24);
            wv[j] = ew[e];
            atomicAdd(&lh[dd >> 8], 1);
        } else key[j] = 0xff000000u;  // invalid bucket marker
    }
    __syncthreads();
    for (int i = t; i < NBUCK; i += 256) {
        lbase[i] = atomicAdd(&gcur[i], lh[i]);
        lcur[i] = 0;
    }
    __syncthreads();
#pragma unroll
    for (int j = 0; j < 16; ++j) {
        int b = key[j] >> 24;
        if (b < NBUCK) {
            int r = atomicAdd(&lcur[b], 1);
            tmp[(size_t)b * CAP + lbase[b] + r] =
                make_uint2(key[j] & 0x00ffffffu, __float_as_uint(wv[j]));
        }
    }
}

// ---------------------------------------------------------------------------
// K2: one block per bucket -> offsets[] + per-node-sorted sw.
// ---------------------------------------------------------------------------
__global__ __launch_bounds__(256) void passB(const int* __restrict__ gcur,
                                             const uint2* __restrict__ tmp,
                                             int* __restrict__ offsets,
                                             uint2* __restrict__ sw) {
    __shared__ int hist[256], ps[256];
    __shared__ int sbase, scnt;
    int b = blockIdx.x, t = threadIdx.x;

    // parallel exclusive scan over bucket counts to get this bucket's base
    int gv = (t < NBUCK) ? gcur[t] : 0;
    ps[t] = gv;
    __syncthreads();
    for (int off = 1; off < 256; off <<= 1) {
        int x = (t >= off) ? ps[t - off] : 0;
        __syncthreads();
        ps[t] += x;
        __syncthreads();
    }
    if (t == b) { sbase = ps[t] - gv; scnt = gv; }
    hist[t] = 0;
    __syncthreads();
    int base = sbase, cnt = scnt;
    const uint2* seg = tmp + (size_t)b * CAP;

    for (int i = t; i < cnt; i += 256) atomicAdd(&hist[seg[i].x >> 16], 1);
    __syncthreads();
    int h = hist[t];
    ps[t] = h;
    __syncthreads();
    for (int off = 1; off < 256; off <<= 1) {
        int x = (t >= off) ? ps[t - off] : 0;
        __syncthreads();
        ps[t] += x;
        __syncthreads();
    }
    int o = base + ps[t] - h;
    int node = b * 256 + t;
    if (node < N_NODES) offsets[node] = o;
    if (b == NBUCK - 1 && t == 0) offsets[N_NODES] = N_EDGES;
    __syncthreads();
    hist[t] = o;  // reuse as cursor
    __syncthreads();
    for (int i = t; i < cnt; i += 256) {
        uint2 u = seg[i];
        int pos = atomicAdd(&hist[u.x >> 16], 1);
        sw[pos] = make_uint2(u.x & 0xffffu, u.y);
    }
}

// ---------------------------------------------------------------------------
// K3 (fused): block = 1024 threads = 16 waves = 16 nodes, ONE node per wave
// (R5-R9 had 4 nodes serialized per wave -> only ~12.5k gather streams
// device-wide; this gives 50k). Per node: one 32-deep asm gather batch
// (covers 99.98% of Poisson(16) nodes in a single vmcnt drain), sw entries
// via coalesced vector load + readlane (no scalar-cache serial path).
// Blended bf16 row -> Arows[wave] -> barrier -> waves 0-3 do the
// 16x128 @ 128x128 MFMA tile (waves 4-15 retire).
// mfma_f32_16x16x32_bf16: A[m=lane&15][k=quad*8+j], B[k][n=lane&15],
// D row=quad*4+reg, col=lane&15 (verified; R2-R9 passed).
// ---------------------------------------------------------------------------
__global__ __launch_bounds__(1024, 2) void agg_gemm(const int* __restrict__ offsets,
                                                    const uint2* __restrict__ sw,
                                                    const unsigned* __restrict__ fb,
                                                    const unsigned short* __restrict__ Wt,
                                                    float* __restrict__ out) {
    __shared__ unsigned Arows[16][68];
    int wave = threadIdx.x >> 6;
    int lane = threadIdx.x & 63;
    unsigned lsh = (unsigned)(lane << 2);  // lane byte offset within a row
    int row0 = blockIdx.x * 16;

    {
        int n = __builtin_amdgcn_readfirstlane(row0 + wave);
        int b = offsets[n], e2 = offsets[n + 1];
        unsigned us = fb[(size_t)n * 64 + lane];  // self row
        float ax = 0.f, ay = 0.f;
        int e = b;
#pragma unroll 1
        while (e < e2) {
            int rem = e2 - e;  // >= 1
            int li = lane & 31;
            uint2 sv = sw[e + (li < rem ? li : rem - 1)];  // coalesced batch
            unsigned u[32];
#pragma unroll
            for (int j = 0; j < 32; ++j) {
                unsigned voff = (__builtin_amdgcn_readlane(sv.x, j) << 8) | lsh;
                asm volatile("global_load_dword %0, %1, %2"
                             : "=v"(u[j]) : "v"(voff), "s"(fb));
            }
            asm volatile("s_waitcnt vmcnt(0)"
                         : "+v"(u[0]), "+v"(u[1]), "+v"(u[2]), "+v"(u[3]),
                           "+v"(u[4]), "+v"(u[5]), "+v"(u[6]), "+v"(u[7]),
                           "+v"(u[8]), "+v"(u[9]), "+v"(u[10]), "+v"(u[11]),
                           "+v"(u[12]), "+v"(u[13]), "+v"(u[14]), "+v"(u[15]),
                           "+v"(u[16]), "+v"(u[17]), "+v"(u[18]), "+v"(u[19]),
                           "+v"(u[20]), "+v"(u[21]), "+v"(u[22]), "+v"(u[23]),
                           "+v"(u[24]), "+v"(u[25]), "+v"(u[26]), "+v"(u[27]),
                           "+v"(u[28]), "+v"(u[29]), "+v"(u[30]), "+v"(u[31])
                         :: "memory");
#pragma unroll
            for (int j = 0; j < 32; ++j) {
                float w = (j < rem)
                    ? __uint_as_float(__builtin_amdgcn_readlane(sv.y, j)) : 0.f;
                ax += w * lo16f(u[j]);
                ay += w * hi16f(u[j]);
            }
            e += 32;
        }
        float rx = 0.5f * (ax + lo16f(us));
        float ry = 0.5f * (ay + hi16f(us));
        Arows[wave][lane] = (unsigned)f2bf(rx) | ((unsigned)f2bf(ry) << 16);
    }
    __syncthreads();

    if (wave < 4) {
        int quad = lane >> 4;
        int col  = lane & 15;
        short8 a[4];
#pragma unroll
        for (int kk = 0; kk < 4; ++kk)
            a[kk] = *reinterpret_cast<const short8*>(&Arows[col][kk * 16 + quad * 4]);

#pragma unroll
        for (int ii = 0; ii < 2; ++ii) {
            int n0 = wave * 2 + ii;
            const short8* bp = reinterpret_cast<const short8*>(Wt) + ((n0 * 16 + col) * 16 + quad);
            f32x4 acc = {0.f, 0.f, 0.f, 0.f};
            acc = __builtin_amdgcn_mfma_f32_16x16x32_bf16(a[0], bp[0],  acc, 0, 0, 0);
            acc = __builtin_amdgcn_mfma_f32_16x16x32_bf16(a[1], bp[4],  acc, 0, 0, 0);
            acc = __builtin_amdgcn_mfma_f32_16x16x32_bf16(a[2], bp[8],  acc, 0, 0, 0);
            acc = __builtin_amdgcn_mfma_f32_16x16x32_bf16(a[3], bp[12], acc, 0, 0, 0);
#pragma unroll
            for (int rr = 0; rr < 4; ++rr)
                out[(size_t)(row0 + quad * 4 + rr) * D + n0 * 16 + col] = acc[rr];
        }
    }
}

// ---------------------------------------------------------------------------
extern "C" void kernel_launch(void* const* d_in, const int* in_sizes, int n_in,
                              void* d_out, int out_size, void* d_ws, size_t ws_size,
                              hipStream_t stream) {
    const float* feat = (const float*)d_in[0];
    const int*   esrc = (const int*)d_in[1];
    const int*   edst = (const int*)d_in[2];
    const float* ew   = (const float*)d_in[3];
    const float* W    = (const float*)d_in[4];
    float*       out  = (float*)d_out;

    char* ws = (char*)d_ws;
    uint2*          sw      = (uint2*)(ws + 0);                   //  6,400,000
    unsigned*       fb      = (unsigned*)(ws + 6400000);          // 12,800,000
    int*            offsets = (int*)(ws + 19200000);              //    200,004
    unsigned short* Wt      = (unsigned short*)(ws + 19400064);   //     32,768
    int*            gcur    = (int*)(ws + 19432832);              //        784
    // tmp (7.53 MB) aliases d_out, dead until agg_gemm overwrites it.
    uint2* tmp = (uint2*)d_out;

    hipMemsetAsync(gcur, 0, NBUCK * sizeof(int), stream);
    prep_passA<<<PA_BLKS + FB_BLKS + WT_BLKS, 256, 0, stream>>>(
        (const float2*)feat, fb, W, Wt, esrc, edst, ew, gcur, tmp);
    passB<<<NBUCK, 256, 0, stream>>>(gcur, tmp, offsets, sw);
    agg_gemm<<<N_NODES / 16, 1024, 0, stream>>>(offsets, sw, fb, Wt, out);
}

// Round 12
// 151.290 us; speedup vs baseline: 1.0720x; 1.0720x over previous
//
#include <hip/hip_runtime.h>

#define N_NODES 50000
#define N_EDGES 800000
#define D 128
#define NBUCK 196   // ceil(50000/256) buckets of 256 nodes (dst>>8)
#define CAP 4800    // per-bucket capacity; mean 4096, sigma ~64 -> 11 sigma
#define CHUNK 4096  // edges per passA block (16/thread)
#define PA_BLKS ((N_EDGES + CHUNK - 1) / CHUNK)  // 196
#define FB_BLKS 12500                            // N_NODES*64/256
#define WT_BLKS 64                               // 16384/256

typedef __attribute__((ext_vector_type(8))) short short8;
typedef __attribute__((ext_vector_type(4))) float f32x4;

__device__ __forceinline__ unsigned short f2bf(float f) {
    unsigned u = __float_as_uint(f);
    u += 0x7fff + ((u >> 16) & 1);  // RNE
    return (unsigned short)(u >> 16);
}
__device__ __forceinline__ float lo16f(unsigned u) { return __uint_as_float(u << 16); }
__device__ __forceinline__ float hi16f(unsigned u) { return __uint_as_float(u & 0xffff0000u); }

// ---------------------------------------------------------------------------
// K1 (fused): passA buckets edges by dst>>8 into tmp (16 edges/thread, packed
// key = src | dlocal<<16 | bucket<<24); prep converts feature -> packed-bf16
// fb and W -> bf16 n-major Wt. gcur pre-zeroed via memsetAsync.
// ---------------------------------------------------------------------------
__global__ __launch_bounds__(256) void prep_passA(
    const float2* __restrict__ feat2, unsigned* __restrict__ fb,
    const float* __restrict__ W, unsigned short* __restrict__ Wt,
    const int* __restrict__ esrc, const int* __restrict__ edst,
    const float* __restrict__ ew, int* __restrict__ gcur,
    uint2* __restrict__ tmp) {
    __shared__ int lh[NBUCK], lbase[NBUCK], lcur[NBUCK];
    int blk = blockIdx.x, t = threadIdx.x;

    if (blk >= PA_BLKS) {
        int b2 = blk - PA_BLKS;
        if (b2 < FB_BLKS) {
            int i = b2 * 256 + t;
            float2 f = feat2[i];
            fb[i] = (unsigned)f2bf(f.x) | ((unsigned)f2bf(f.y) << 16);
        } else {
            int idx = (b2 - FB_BLKS) * 256 + t;  // 16384 weight elements
            int n = idx >> 7, k = idx & 127;
            Wt[idx] = f2bf(W[k * 128 + n]);
        }
        return;
    }

    // ---- passA ----
    for (int i = t; i < NBUCK; i += 256) lh[i] = 0;
    __syncthreads();
    int e0 = blk * CHUNK;
    unsigned key[16];
    float wv[16];
#pragma unroll
    for (int j = 0; j < 16; ++j) {
        int e = e0 + j * 256 + t;
        if (e < N_EDGES) {
            int src = esrc[e], dd = edst[e];
            key[j] = (unsigned)src | ((unsigned)(dd & 255) << 16) |
                     ((unsigned)(dd >> 8) << 24);
            wv[j] = ew[e];
            atomicAdd(&lh[dd >> 8], 1);
        } else key[j] = 0xff000000u;  // invalid bucket marker
    }
    __syncthreads();
    for (int i = t; i < NBUCK; i += 256) {
        lbase[i] = atomicAdd(&gcur[i], lh[i]);
        lcur[i] = 0;
    }
    __syncthreads();
#pragma unroll
    for (int j = 0; j < 16; ++j) {
        int b = key[j] >> 24;
        if (b < NBUCK) {
            int r = atomicAdd(&lcur[b], 1);
            tmp[(size_t)b * CAP + lbase[b] + r] =
                make_uint2(key[j] & 0x00ffffffu, __float_as_uint(wv[j]));
        }
    }
}

// ---------------------------------------------------------------------------
// K2: one block per bucket -> offsets[] + per-node-sorted sw.
// ---------------------------------------------------------------------------
__global__ __launch_bounds__(256) void passB(const int* __restrict__ gcur,
                                             const uint2* __restrict__ tmp,
                                             int* __restrict__ offsets,
                                             uint2* __restrict__ sw) {
    __shared__ int hist[256], ps[256];
    __shared__ int sbase, scnt;
    int b = blockIdx.x, t = threadIdx.x;

    // parallel exclusive scan over bucket counts to get this bucket's base
    int gv = (t < NBUCK) ? gcur[t] : 0;
    ps[t] = gv;
    __syncthreads();
    for (int off = 1; off < 256; off <<= 1) {
        int x = (t >= off) ? ps[t - off] : 0;
        __syncthreads();
        ps[t] += x;
        __syncthreads();
    }
    if (t == b) { sbase = ps[t] - gv; scnt = gv; }
    hist[t] = 0;
    __syncthreads();
    int base = sbase, cnt = scnt;
    const uint2* seg = tmp + (size_t)b * CAP;

    for (int i = t; i < cnt; i += 256) atomicAdd(&hist[seg[i].x >> 16], 1);
    __syncthreads();
    int h = hist[t];
    ps[t] = h;
    __syncthreads();
    for (int off = 1; off < 256; off <<= 1) {
        int x = (t >= off) ? ps[t - off] : 0;
        __syncthreads();
        ps[t] += x;
        __syncthreads();
    }
    int o = base + ps[t] - h;
    int node = b * 256 + t;
    if (node < N_NODES) offsets[node] = o;
    if (b == NBUCK - 1 && t == 0) offsets[N_NODES] = N_EDGES;
    __syncthreads();
    hist[t] = o;  // reuse as cursor
    __syncthreads();
    for (int i = t; i < cnt; i += 256) {
        uint2 u = seg[i];
        int pos = atomicAdd(&hist[u.x >> 16], 1);
        sw[pos] = make_uint2(u.x & 0xffffu, u.y);
    }
}

// ---------------------------------------------------------------------------
// K3 (fused): block = 16 nodes, wave aggregates 4 (lane owns cols 2*lane,
// 2*lane+1), 16-deep gather unroll -- the best-measured variant of the six
// tried (R5: 44.1us, VGPR 28; LDS-DMA/paired-lanes/asm-MLP/wave-remap all
// 46-56us). Gather phase is L2-fill bound: each XCD streams ~11MB of the
// 12.8MB fb table through its private L2 (~86MB total fills, matches FETCH).
// Blended bf16 rows -> Arows -> 16x128 @ 128x128 MFMA.
// mfma_f32_16x16x32_bf16: A[m=lane&15][k=quad*8+j], B[k][n=lane&15],
// D row=quad*4+reg, col=lane&15 (verified; R2-R10 passed).
// ---------------------------------------------------------------------------
__global__ __launch_bounds__(256) void agg_gemm(const int* __restrict__ offsets,
                                                const uint2* __restrict__ sw,
                                                const unsigned* __restrict__ fb,
                                                const unsigned short* __restrict__ Wt,
                                                float* __restrict__ out) {
    __shared__ unsigned Arows[16][68];
    int wave = threadIdx.x >> 6;
    int lane = threadIdx.x & 63;
    int row0 = blockIdx.x * 16;

#pragma unroll 1
    for (int i = 0; i < 4; ++i) {
        int n = __builtin_amdgcn_readfirstlane(row0 + wave * 4 + i);
        int b = offsets[n], e2 = offsets[n + 1];
        unsigned us = fb[(size_t)n * 64 + lane];  // self row, independent load
        float ax = 0.f, ay = 0.f;
        int e = b;
        for (; e + 16 <= e2; e += 16) {
            uint2 p[16];
            unsigned u[16];
#pragma unroll
            for (int j = 0; j < 16; ++j) p[j] = sw[e + j];
#pragma unroll
            for (int j = 0; j < 16; ++j) u[j] = fb[(size_t)p[j].x * 64 + lane];
#pragma unroll
            for (int j = 0; j < 16; ++j) {
                float w = __uint_as_float(p[j].y);
                ax += w * lo16f(u[j]);
                ay += w * hi16f(u[j]);
            }
        }
        if (e + 8 <= e2) {
            uint2 p[8];
            unsigned u[8];
#pragma unroll
            for (int j = 0; j < 8; ++j) p[j] = sw[e + j];
#pragma unroll
            for (int j = 0; j < 8; ++j) u[j] = fb[(size_t)p[j].x * 64 + lane];
#pragma unroll
            for (int j = 0; j < 8; ++j) {
                float w = __uint_as_float(p[j].y);
                ax += w * lo16f(u[j]);
                ay += w * hi16f(u[j]);
            }
            e += 8;
        }
        for (; e < e2; ++e) {
            uint2 p = sw[e];
            unsigned u = fb[(size_t)p.x * 64 + lane];
            float w = __uint_as_float(p.y);
            ax += w * lo16f(u);
            ay += w * hi16f(u);
        }
        float rx = 0.5f * (ax + lo16f(us));
        float ry = 0.5f * (ay + hi16f(us));
        Arows[wave * 4 + i][lane] = (unsigned)f2bf(rx) | ((unsigned)f2bf(ry) << 16);
    }
    __syncthreads();

    int quad = lane >> 4;
    int col  = lane & 15;
    short8 a[4];
#pragma unroll
    for (int kk = 0; kk < 4; ++kk)
        a[kk] = *reinterpret_cast<const short8*>(&Arows[col][kk * 16 + quad * 4]);

#pragma unroll
    for (int ii = 0; ii < 2; ++ii) {
        int n0 = wave * 2 + ii;
        const short8* bp = reinterpret_cast<const short8*>(Wt) + ((n0 * 16 + col) * 16 + quad);
        f32x4 acc = {0.f, 0.f, 0.f, 0.f};
        acc = __builtin_amdgcn_mfma_f32_16x16x32_bf16(a[0], bp[0],  acc, 0, 0, 0);
        acc = __builtin_amdgcn_mfma_f32_16x16x32_bf16(a[1], bp[4],  acc, 0, 0, 0);
        acc = __builtin_amdgcn_mfma_f32_16x16x32_bf16(a[2], bp[8],  acc, 0, 0, 0);
        acc = __builtin_amdgcn_mfma_f32_16x16x32_bf16(a[3], bp[12], acc, 0, 0, 0);
#pragma unroll
        for (int rr = 0; rr < 4; ++rr)
            out[(size_t)(row0 + quad * 4 + rr) * D + n0 * 16 + col] = acc[rr];
    }
}

// ---------------------------------------------------------------------------
extern "C" void kernel_launch(void* const* d_in, const int* in_sizes, int n_in,
                              void* d_out, int out_size, void* d_ws, size_t ws_size,
                              hipStream_t stream) {
    const float* feat = (const float*)d_in[0];
    const int*   esrc = (const int*)d_in[1];
    const int*   edst = (const int*)d_in[2];
    const float* ew   = (const float*)d_in[3];
    const float* W    = (const float*)d_in[4];
    float*       out  = (float*)d_out;

    char* ws = (char*)d_ws;
    uint2*          sw      = (uint2*)(ws + 0);                   //  6,400,000
    unsigned*       fb      = (unsigned*)(ws + 6400000);          // 12,800,000
    int*            offsets = (int*)(ws + 19200000);              //    200,004
    unsigned short* Wt      = (unsigned short*)(ws + 19400064);   //     32,768
    int*            gcur    = (int*)(ws + 19432832);              //        784
    // tmp (7.53 MB) aliases d_out, dead until agg_gemm overwrites it.
    uint2* tmp = (uint2*)d_out;

    hipMemsetAsync(gcur, 0, NBUCK * sizeof(int), stream);
    prep_passA<<<PA_BLKS + FB_BLKS + WT_BLKS, 256, 0, stream>>>(
        (const float2*)feat, fb, W, Wt, esrc, edst, ew, gcur, tmp);
    passB<<<NBUCK, 256, 0, stream>>>(gcur, tmp, offsets, sw);
    agg_gemm<<<N_NODES / 16, 256, 0, stream>>>(offsets, sw, fb, Wt, out);
}